// Round 2
// baseline (818.454 us; speedup 1.0000x reference)
//
#include <hip/hip_runtime.h>
#include <math.h>

#define NNODES 50000
#define NEDGES 800000
// D = 128 fixed

// ---------------------------------------------------------------- utilities
static __device__ __forceinline__ float wave_sum64(float v) {
#pragma unroll
  for (int off = 32; off > 0; off >>= 1)
    v += __shfl_xor(v, off, 64);
  return v;
}

// ------------------------------------------------- W transpose (6 matrices)
// wt[mat][i][o] = W_mat[o][i]; mat order: Wl0,Wr0,Wl1,Wr1,Wl2,Wr2
__global__ __launch_bounds__(256) void transpose_w(
    const float* __restrict__ w0, const float* __restrict__ w1,
    const float* __restrict__ w2, const float* __restrict__ w3,
    const float* __restrict__ w4, const float* __restrict__ w5,
    float* __restrict__ wt)
{
  int g = blockIdx.x * 256 + threadIdx.x;   // 0..98303  (= 6*16384)
  int mat = g >> 14;
  int r = g & 16383;
  int o = r >> 7;
  int i = r & 127;
  const float* s = w0;
  if (mat == 1) s = w1; else if (mat == 2) s = w2; else if (mat == 3) s = w3;
  else if (mat == 4) s = w4; else if (mat == 5) s = w5;
  float v = s[r];                       // W[o*128+i], coalesced read
  wt[mat * 16384 + i * 128 + o] = v;    // strided write, tiny one-time cost
}

// ------------------------------------------------------------- CSR build
// NOTE: harness uploads integer inputs as int32 — edge_index is const int*.
__global__ __launch_bounds__(256) void hist_kernel(
    const int* __restrict__ ei, int* __restrict__ counts)
{
  int e = blockIdx.x * 256 + threadIdx.x;
  if (e < NEDGES) {
    int d = ei[NEDGES + e];             // dst row of edge_index
    atomicAdd(&counts[d], 1);
  }
}

// single block, 1024 threads: rowptr[i+1]-rowptr[i] = counts[i]+1 (self loop)
__global__ __launch_bounds__(1024) void scan_kernel(
    const int* __restrict__ counts, int* __restrict__ rowptr,
    int* __restrict__ cursor)
{
  __shared__ int sums[1024];
  const int CH = 49;                    // 1024*49 = 50176 >= 50000
  int tid = threadIdx.x;
  int base = tid * CH;
  int s = 0;
  for (int j = 0; j < CH; ++j) {
    int idx = base + j;
    if (idx < NNODES) s += counts[idx] + 1;
  }
  sums[tid] = s;
  __syncthreads();
  for (int off = 1; off < 1024; off <<= 1) {
    int v = (tid >= off) ? sums[tid - off] : 0;
    __syncthreads();
    sums[tid] += v;
    __syncthreads();
  }
  int run = (tid == 0) ? 0 : sums[tid - 1];
  for (int j = 0; j < CH; ++j) {
    int idx = base + j;
    if (idx < NNODES) {
      int c = counts[idx];              // read BEFORE writes (alias-safe)
      rowptr[idx] = run;
      cursor[idx] = run;
      run += c + 1;
    }
  }
  if (tid == 0) rowptr[NNODES] = sums[1023];   // = NEDGES + NNODES
}

__global__ __launch_bounds__(256) void scatter_kernel(
    const int* __restrict__ ei, int* __restrict__ cursor,
    int* __restrict__ col)
{
  int e = blockIdx.x * 256 + threadIdx.x;
  if (e < NEDGES + NNODES) {
    int s, d;
    if (e < NEDGES) { s = ei[e]; d = ei[NEDGES + e]; }
    else           { s = e - NEDGES; d = s; }   // self loop
    int slot = atomicAdd(&cursor[d], 1);
    col[slot] = s;
  }
}

// ------------------------------------------------------- fused dual GEMM
// xl[n][o] = sum_i h[n][i]*Wl[o][i];  xr likewise. wlT/wrT are [i][o].
// Block: 256 threads, 64-node tile. Thread: 8 nodes x 4 outs x 2 mats.
__global__ __launch_bounds__(256, 2) void gemm_xlxr(
    const float* __restrict__ h, const float* __restrict__ wlT,
    const float* __restrict__ wrT, float* __restrict__ xl,
    float* __restrict__ xr)
{
  __shared__ float hs[64][132];          // pad 132 keeps reads conflict-cheap
  const int tid = threadIdx.x;
  const int n0 = blockIdx.x * 64;
  const float4* h4 = (const float4*)h;
#pragma unroll
  for (int it = 0; it < 8; ++it) {
    int f = it * 256 + tid;              // 0..2047
    int n = f >> 5;                      // 0..63
    int c = f & 31;                      // float4 column
    float4 v = make_float4(0.f, 0.f, 0.f, 0.f);
    if (n0 + n < NNODES) v = h4[(n0 + n) * 32 + c];
    *((float4*)&hs[n][4 * c]) = v;
  }
  __syncthreads();

  const int to = tid & 31;               // o = to*4 .. to*4+3
  const int tg = tid >> 5;               // node group: n = tg*8 + j
  float4 accl[8], accr[8];
#pragma unroll
  for (int j = 0; j < 8; ++j) {
    accl[j] = make_float4(0.f, 0.f, 0.f, 0.f);
    accr[j] = make_float4(0.f, 0.f, 0.f, 0.f);
  }
  const float4* wl4 = (const float4*)wlT;
  const float4* wr4 = (const float4*)wrT;
#pragma unroll 2
  for (int i = 0; i < 128; ++i) {
    float4 wl = wl4[i * 32 + to];        // L1/L2 resident (128 KB total)
    float4 wr = wr4[i * 32 + to];
#pragma unroll
    for (int j = 0; j < 8; ++j) {
      float hv = hs[tg * 8 + j][i];      // broadcast across 32 lanes
      accl[j].x = fmaf(hv, wl.x, accl[j].x);
      accl[j].y = fmaf(hv, wl.y, accl[j].y);
      accl[j].z = fmaf(hv, wl.z, accl[j].z);
      accl[j].w = fmaf(hv, wl.w, accl[j].w);
      accr[j].x = fmaf(hv, wr.x, accr[j].x);
      accr[j].y = fmaf(hv, wr.y, accr[j].y);
      accr[j].z = fmaf(hv, wr.z, accr[j].z);
      accr[j].w = fmaf(hv, wr.w, accr[j].w);
    }
  }
#pragma unroll
  for (int j = 0; j < 8; ++j) {
    int n = n0 + tg * 8 + j;
    if (n < NNODES) {
      ((float4*)xl)[n * 32 + to] = accl[j];
      ((float4*)xr)[n * 32 + to] = accr[j];
    }
  }
}

// ---------------------------------------- fused attention + aggregate + GELU
// One wave per dst node; lane holds features {2*lane, 2*lane+1}.
// Online softmax over incoming edges; epilogue adds bias and applies exact GELU.
__global__ __launch_bounds__(256) void agg_kernel(
    const int* __restrict__ rowptr, const int* __restrict__ col,
    const float* __restrict__ xl, const float* __restrict__ xr,
    const float* __restrict__ att, const float* __restrict__ bias,
    float* __restrict__ hout)
{
  const int lane = threadIdx.x & 63;
  const int d = blockIdx.x * 4 + (threadIdx.x >> 6);

  const float2* xl2 = (const float2*)xl;
  float2 xrv = ((const float2*)xr)[d * 64 + lane];
  float2 av  = ((const float2*)att)[lane];
  int beg = rowptr[d], end = rowptr[d + 1];

  float mx = -INFINITY, den = 0.f;
  float a0 = 0.f, a1 = 0.f;
  for (int k = beg; k < end; ++k) {
    int s = col[k];                       // wave-uniform
    float2 v = xl2[s * 64 + lane];        // 512 B gather, L3-resident
    float m0 = v.x + xrv.x, m1 = v.y + xrv.y;
    m0 = fmaxf(m0, 0.2f * m0);            // LeakyReLU(0.2)
    m1 = fmaxf(m1, 0.2f * m1);
    float p = wave_sum64(fmaf(m0, av.x, m1 * av.y));   // logit e
    float nm = fmaxf(mx, p);
    float sc = __expf(mx - nm);           // first iter: exp(-inf)=0
    float w  = __expf(p - nm);
    den = den * sc + w;
    a0  = fmaf(w, v.x, a0 * sc);
    a1  = fmaf(w, v.y, a1 * sc);
    mx = nm;
  }
  float inv = 1.f / den;
  float o0 = fmaf(a0, inv, bias[2 * lane]);
  float o1 = fmaf(a1, inv, bias[2 * lane + 1]);
  o0 = 0.5f * o0 * (1.f + erff(o0 * 0.70710678118654752f));
  o1 = 0.5f * o1 * (1.f + erff(o1 * 0.70710678118654752f));
  ((float2*)hout)[d * 64 + lane] = make_float2(o0, o1);
}

// ------------------------------------------------------------------ launch
extern "C" void kernel_launch(void* const* d_in, const int* in_sizes, int n_in,
                              void* d_out, int out_size, void* d_ws, size_t ws_size,
                              hipStream_t stream)
{
  const float* x = (const float*)d_in[0];
  const int* ei = (const int*)d_in[1];     // int inputs arrive as int32
  const float *Wl[3], *Wr[3], *attv[3], *bv[3];
  for (int l = 0; l < 3; ++l) {
    Wl[l]   = (const float*)d_in[2 + 4 * l];
    Wr[l]   = (const float*)d_in[3 + 4 * l];
    attv[l] = (const float*)d_in[4 + 4 * l];
    bv[l]   = (const float*)d_in[5 + 4 * l];
  }

  char* base = (char*)d_ws;
  size_t off = 0;
  auto alloc = [&](size_t bytes) -> char* {
    char* p = base + off;
    off += (bytes + 255) & ~(size_t)255;
    return p;
  };
  float* wt     = (float*)alloc((size_t)6 * 16384 * 4);
  float* xl     = (float*)alloc((size_t)NNODES * 128 * 4);
  float* xr     = (float*)alloc((size_t)NNODES * 128 * 4);
  int* rowptr   = (int*)alloc((size_t)(NNODES + 1) * 4);
  int* cursor   = (int*)alloc((size_t)NNODES * 4);
  int* counts   = (int*)alloc((size_t)NNODES * 4);
  int* col      = (int*)alloc((size_t)(NEDGES + NNODES) * 4);
  (void)ws_size; (void)in_sizes; (void)n_in; (void)out_size;

  hipMemsetAsync(counts, 0, (size_t)NNODES * 4, stream);
  transpose_w<<<384, 256, 0, stream>>>(Wl[0], Wr[0], Wl[1], Wr[1], Wl[2], Wr[2], wt);
  hist_kernel<<<(NEDGES + 255) / 256, 256, 0, stream>>>(ei, counts);
  scan_kernel<<<1, 1024, 0, stream>>>(counts, rowptr, cursor);
  scatter_kernel<<<(NEDGES + NNODES + 255) / 256, 256, 0, stream>>>(ei, cursor, col);

  // h ping-pongs through d_out: each layer's GEMM consumes h before agg
  // overwrites it, and agg never reads its own output buffer.
  float* dout = (float*)d_out;
  const float* hin = x;
  for (int l = 0; l < 3; ++l) {
    gemm_xlxr<<<(NNODES + 63) / 64, 256, 0, stream>>>(
        hin, wt + (size_t)(2 * l) * 16384, wt + (size_t)(2 * l + 1) * 16384, xl, xr);
    agg_kernel<<<NNODES / 4, 256, 0, stream>>>(
        rowptr, col, xl, xr, attv[l], bv[l], dout);
    hin = dout;
  }
}

// Round 3
// 552.025 us; speedup vs baseline: 1.4826x; 1.4826x over previous
//
#include <hip/hip_runtime.h>
#include <math.h>

#define NNODES 50000
#define NEDGES 800000
#define NBLK 196   // ceil(50000/256)
// D = 128 fixed

// ------------------------------------------------- W transpose (6 matrices)
// wt[mat][i][o] = W_mat[o][i]; mat order: Wl0,Wr0,Wl1,Wr1,Wl2,Wr2
__global__ __launch_bounds__(256) void transpose_w(
    const float* __restrict__ w0, const float* __restrict__ w1,
    const float* __restrict__ w2, const float* __restrict__ w3,
    const float* __restrict__ w4, const float* __restrict__ w5,
    float* __restrict__ wt)
{
  int g = blockIdx.x * 256 + threadIdx.x;   // 0..98303  (= 6*16384)
  int mat = g >> 14;
  int r = g & 16383;
  int o = r >> 7;
  int i = r & 127;
  const float* s = w0;
  if (mat == 1) s = w1; else if (mat == 2) s = w2; else if (mat == 3) s = w3;
  else if (mat == 4) s = w4; else if (mat == 5) s = w5;
  float v = s[r];                       // W[o*128+i], coalesced read
  wt[mat * 16384 + i * 128 + o] = v;    // strided write, tiny one-time cost
}

// ------------------------------------------------------------- CSR build
// Harness uploads integer inputs as int32 — edge_index is const int*.
__global__ __launch_bounds__(256) void hist_kernel(
    const int* __restrict__ ei, int* __restrict__ counts)
{
  int e = blockIdx.x * 256 + threadIdx.x;
  if (e < NEDGES) {
    int d = ei[NEDGES + e];             // dst row of edge_index
    atomicAdd(&counts[d], 1);
  }
}

// Hierarchical scan of (counts[i]+1), 50000 elems, exclusive.
// Pass 1: per-block (256-elem) scan; part[i] = exclusive-in-block, bsum[b] = block total.
__global__ __launch_bounds__(256) void scan_part(
    const int* __restrict__ counts, int* __restrict__ part,
    int* __restrict__ bsum)
{
  __shared__ int sh[256];
  int t = threadIdx.x;
  int i = blockIdx.x * 256 + t;
  int v = (i < NNODES) ? counts[i] + 1 : 0;   // +1 = self loop slot
  sh[t] = v;
  __syncthreads();
  for (int off = 1; off < 256; off <<= 1) {
    int u = (t >= off) ? sh[t - off] : 0;
    __syncthreads();
    sh[t] += u;
    __syncthreads();
  }
  if (i < NNODES) part[i] = sh[t] - v;        // exclusive
  if (t == 255) bsum[blockIdx.x] = sh[255];
}

// Pass 2: single block scans the 196 block sums (in place -> exclusive).
__global__ __launch_bounds__(256) void scan_bsums(int* __restrict__ bsum)
{
  __shared__ int sh[256];
  int t = threadIdx.x;
  int v = (t < NBLK) ? bsum[t] : 0;
  sh[t] = v;
  __syncthreads();
  for (int off = 1; off < 256; off <<= 1) {
    int u = (t >= off) ? sh[t - off] : 0;
    __syncthreads();
    sh[t] += u;
    __syncthreads();
  }
  if (t < NBLK) bsum[t] = sh[t] - v;          // exclusive
}

// Pass 3: rowptr[i] = part[i] + bsum[block]; also init cursor.
__global__ __launch_bounds__(256) void scan_final(
    const int* __restrict__ part, const int* __restrict__ bsum,
    int* __restrict__ rowptr, int* __restrict__ cursor)
{
  int i = blockIdx.x * 256 + threadIdx.x;
  if (i < NNODES) {
    int r = part[i] + bsum[blockIdx.x];
    rowptr[i] = r;
    cursor[i] = r;
  }
  if (i == 0) rowptr[NNODES] = NEDGES + NNODES;
}

__global__ __launch_bounds__(256) void scatter_kernel(
    const int* __restrict__ ei, int* __restrict__ cursor,
    int* __restrict__ col)
{
  int e = blockIdx.x * 256 + threadIdx.x;
  if (e < NEDGES + NNODES) {
    int s, d;
    if (e < NEDGES) { s = ei[e]; d = ei[NEDGES + e]; }
    else           { s = e - NEDGES; d = s; }   // self loop
    int slot = atomicAdd(&cursor[d], 1);
    col[slot] = s;
  }
}

// ------------------------------------------------------- fused dual GEMM
// xl[n][o] = sum_i h[n][i]*Wl[o][i];  xr likewise. wlT/wrT are [i][o].
// Block: 256 threads, 64-node tile. Thread: 8 nodes x 4 outs x 2 mats.
// launch_bounds(256,4): 4 blocks/CU (LDS 4x33.8=135KB<=160) hides W L2 latency.
__global__ __launch_bounds__(256, 4) void gemm_xlxr(
    const float* __restrict__ h, const float* __restrict__ wlT,
    const float* __restrict__ wrT, float* __restrict__ xl,
    float* __restrict__ xr)
{
  __shared__ float hs[64][132];          // pad 132 keeps reads conflict-cheap
  const int tid = threadIdx.x;
  const int n0 = blockIdx.x * 64;
  const float4* h4 = (const float4*)h;
#pragma unroll
  for (int it = 0; it < 8; ++it) {
    int f = it * 256 + tid;              // 0..2047
    int n = f >> 5;                      // 0..63
    int c = f & 31;                      // float4 column
    float4 v = make_float4(0.f, 0.f, 0.f, 0.f);
    if (n0 + n < NNODES) v = h4[(n0 + n) * 32 + c];
    *((float4*)&hs[n][4 * c]) = v;
  }
  __syncthreads();

  const int to = tid & 31;               // o = to*4 .. to*4+3
  const int tg = tid >> 5;               // node group: n = tg*8 + j
  float4 accl[8], accr[8];
#pragma unroll
  for (int j = 0; j < 8; ++j) {
    accl[j] = make_float4(0.f, 0.f, 0.f, 0.f);
    accr[j] = make_float4(0.f, 0.f, 0.f, 0.f);
  }
  const float4* wl4 = (const float4*)wlT;
  const float4* wr4 = (const float4*)wrT;
#pragma unroll 4
  for (int i = 0; i < 128; ++i) {
    float4 wl = wl4[i * 32 + to];        // L2 resident (128 KB total)
    float4 wr = wr4[i * 32 + to];
#pragma unroll
    for (int j = 0; j < 8; ++j) {
      float hv = hs[tg * 8 + j][i];      // broadcast across 32 lanes
      accl[j].x = fmaf(hv, wl.x, accl[j].x);
      accl[j].y = fmaf(hv, wl.y, accl[j].y);
      accl[j].z = fmaf(hv, wl.z, accl[j].z);
      accl[j].w = fmaf(hv, wl.w, accl[j].w);
      accr[j].x = fmaf(hv, wr.x, accr[j].x);
      accr[j].y = fmaf(hv, wr.y, accr[j].y);
      accr[j].z = fmaf(hv, wr.z, accr[j].z);
      accr[j].w = fmaf(hv, wr.w, accr[j].w);
    }
  }
#pragma unroll
  for (int j = 0; j < 8; ++j) {
    int n = n0 + tg * 8 + j;
    if (n < NNODES) {
      ((float4*)xl)[n * 32 + to] = accl[j];
      ((float4*)xr)[n * 32 + to] = accr[j];
    }
  }
}

// ---------------------------------------- fused attention + aggregate + GELU
// One wave per dst node; lane holds features {2*lane, 2*lane+1}.
// 4 independent online-softmax states -> 4 gather+reduce chains in flight;
// merged at the end. Epilogue: bias + exact GELU.
struct OState { float mx, dn, a0, a1; };

static __device__ __forceinline__ void upd_state(
    OState& st, float q, float vx, float vy)
{
  float nm = fmaxf(st.mx, q);
  float sc = __expf(st.mx - nm);        // first use: exp(-inf)=0
  float w  = __expf(q - nm);
  st.dn = fmaf(st.dn, sc, w);
  st.a0 = fmaf(st.a0, sc, w * vx);
  st.a1 = fmaf(st.a1, sc, w * vy);
  st.mx = nm;
}

__global__ __launch_bounds__(256) void agg_kernel(
    const int* __restrict__ rowptr, const int* __restrict__ col,
    const float* __restrict__ xl, const float* __restrict__ xr,
    const float* __restrict__ att, const float* __restrict__ bias,
    float* __restrict__ hout)
{
  const int lane = threadIdx.x & 63;
  const int d = blockIdx.x * 4 + (threadIdx.x >> 6);

  const float2* xl2 = (const float2*)xl;
  float2 xrv = ((const float2*)xr)[d * 64 + lane];
  float2 av  = ((const float2*)att)[lane];
  int beg = rowptr[d], end = rowptr[d + 1];

  OState s0 = {-INFINITY, 0.f, 0.f, 0.f};
  OState s1 = {-INFINITY, 0.f, 0.f, 0.f};
  OState s2 = {-INFINITY, 0.f, 0.f, 0.f};
  OState s3 = {-INFINITY, 0.f, 0.f, 0.f};

  int k = beg;
  for (; k + 4 <= end; k += 4) {
    int c0 = col[k], c1 = col[k + 1], c2 = col[k + 2], c3 = col[k + 3];
    float2 v0 = xl2[c0 * 64 + lane];
    float2 v1 = xl2[c1 * 64 + lane];
    float2 v2 = xl2[c2 * 64 + lane];
    float2 v3 = xl2[c3 * 64 + lane];
    float m0x = v0.x + xrv.x, m0y = v0.y + xrv.y;
    float m1x = v1.x + xrv.x, m1y = v1.y + xrv.y;
    float m2x = v2.x + xrv.x, m2y = v2.y + xrv.y;
    float m3x = v3.x + xrv.x, m3y = v3.y + xrv.y;
    m0x = fmaxf(m0x, 0.2f * m0x); m0y = fmaxf(m0y, 0.2f * m0y);
    m1x = fmaxf(m1x, 0.2f * m1x); m1y = fmaxf(m1y, 0.2f * m1y);
    m2x = fmaxf(m2x, 0.2f * m2x); m2y = fmaxf(m2y, 0.2f * m2y);
    m3x = fmaxf(m3x, 0.2f * m3x); m3y = fmaxf(m3y, 0.2f * m3y);
    float q0 = fmaf(m0x, av.x, m0y * av.y);
    float q1 = fmaf(m1x, av.x, m1y * av.y);
    float q2 = fmaf(m2x, av.x, m2y * av.y);
    float q3 = fmaf(m3x, av.x, m3y * av.y);
#pragma unroll
    for (int off = 32; off > 0; off >>= 1) {   // 4 independent chains
      q0 += __shfl_xor(q0, off, 64);
      q1 += __shfl_xor(q1, off, 64);
      q2 += __shfl_xor(q2, off, 64);
      q3 += __shfl_xor(q3, off, 64);
    }
    upd_state(s0, q0, v0.x, v0.y);
    upd_state(s1, q1, v1.x, v1.y);
    upd_state(s2, q2, v2.x, v2.y);
    upd_state(s3, q3, v3.x, v3.y);
  }
  for (; k < end; ++k) {                       // <=3 remainder edges
    int c = col[k];
    float2 v = xl2[c * 64 + lane];
    float mx0 = v.x + xrv.x, my0 = v.y + xrv.y;
    mx0 = fmaxf(mx0, 0.2f * mx0); my0 = fmaxf(my0, 0.2f * my0);
    float q = fmaf(mx0, av.x, my0 * av.y);
#pragma unroll
    for (int off = 32; off > 0; off >>= 1) q += __shfl_xor(q, off, 64);
    upd_state(s0, q, v.x, v.y);
  }

  // merge the 4 states (unused states have mx=-inf -> weight 0)
  float M = fmaxf(fmaxf(s0.mx, s1.mx), fmaxf(s2.mx, s3.mx));
  float e0 = __expf(s0.mx - M), e1 = __expf(s1.mx - M);
  float e2 = __expf(s2.mx - M), e3 = __expf(s3.mx - M);
  float den = s0.dn * e0 + s1.dn * e1 + s2.dn * e2 + s3.dn * e3;
  float a0  = s0.a0 * e0 + s1.a0 * e1 + s2.a0 * e2 + s3.a0 * e3;
  float a1  = s0.a1 * e0 + s1.a1 * e1 + s2.a1 * e2 + s3.a1 * e3;

  float inv = 1.f / den;
  float o0 = fmaf(a0, inv, bias[2 * lane]);
  float o1 = fmaf(a1, inv, bias[2 * lane + 1]);
  o0 = 0.5f * o0 * (1.f + erff(o0 * 0.70710678118654752f));
  o1 = 0.5f * o1 * (1.f + erff(o1 * 0.70710678118654752f));
  ((float2*)hout)[d * 64 + lane] = make_float2(o0, o1);
}

// ------------------------------------------------------------------ launch
extern "C" void kernel_launch(void* const* d_in, const int* in_sizes, int n_in,
                              void* d_out, int out_size, void* d_ws, size_t ws_size,
                              hipStream_t stream)
{
  const float* x = (const float*)d_in[0];
  const int* ei = (const int*)d_in[1];     // int inputs arrive as int32
  const float *Wl[3], *Wr[3], *attv[3], *bv[3];
  for (int l = 0; l < 3; ++l) {
    Wl[l]   = (const float*)d_in[2 + 4 * l];
    Wr[l]   = (const float*)d_in[3 + 4 * l];
    attv[l] = (const float*)d_in[4 + 4 * l];
    bv[l]   = (const float*)d_in[5 + 4 * l];
  }

  char* base = (char*)d_ws;
  size_t off = 0;
  auto alloc = [&](size_t bytes) -> char* {
    char* p = base + off;
    off += (bytes + 255) & ~(size_t)255;
    return p;
  };
  float* wt     = (float*)alloc((size_t)6 * 16384 * 4);
  float* xl     = (float*)alloc((size_t)NNODES * 128 * 4);
  float* xr     = (float*)alloc((size_t)NNODES * 128 * 4);
  int* rowptr   = (int*)alloc((size_t)(NNODES + 1) * 4);
  int* cursor   = (int*)alloc((size_t)NNODES * 4);
  int* counts   = (int*)alloc((size_t)NNODES * 4);
  int* part     = (int*)alloc((size_t)(NBLK * 256) * 4);
  int* bsum     = (int*)alloc((size_t)256 * 4);
  int* col      = (int*)alloc((size_t)(NEDGES + NNODES) * 4);
  (void)ws_size; (void)in_sizes; (void)n_in; (void)out_size;

  hipMemsetAsync(counts, 0, (size_t)NNODES * 4, stream);
  transpose_w<<<384, 256, 0, stream>>>(Wl[0], Wr[0], Wl[1], Wr[1], Wl[2], Wr[2], wt);
  hist_kernel<<<(NEDGES + 255) / 256, 256, 0, stream>>>(ei, counts);
  scan_part<<<NBLK, 256, 0, stream>>>(counts, part, bsum);
  scan_bsums<<<1, 256, 0, stream>>>(bsum);
  scan_final<<<NBLK, 256, 0, stream>>>(part, bsum, rowptr, cursor);
  scatter_kernel<<<(NEDGES + NNODES + 255) / 256, 256, 0, stream>>>(ei, cursor, col);

  // h ping-pongs through d_out: each layer's GEMM consumes h before agg
  // overwrites it, and agg never reads its own output buffer.
  float* dout = (float*)d_out;
  const float* hin = x;
  for (int l = 0; l < 3; ++l) {
    gemm_xlxr<<<(NNODES + 63) / 64, 256, 0, stream>>>(
        hin, wt + (size_t)(2 * l) * 16384, wt + (size_t)(2 * l + 1) * 16384, xl, xr);
    agg_kernel<<<NNODES / 4, 256, 0, stream>>>(
        rowptr, col, xl, xr, attv[l], bv[l], dout);
    hin = dout;
  }
}

// Round 4
// 544.125 us; speedup vs baseline: 1.5042x; 1.0145x over previous
//
#include <hip/hip_runtime.h>
#include <math.h>
#include <float.h>

#define NNODES 50000
#define NEDGES 800000
#define NBLK 196   // ceil(50000/256)
// D = 128 fixed

// ------------------------------------------------- W transpose (6 matrices)
// wt[mat][i][o] = W_mat[o][i]; mat order: Wl0,Wr0,Wl1,Wr1,Wl2,Wr2
__global__ __launch_bounds__(256) void transpose_w(
    const float* __restrict__ w0, const float* __restrict__ w1,
    const float* __restrict__ w2, const float* __restrict__ w3,
    const float* __restrict__ w4, const float* __restrict__ w5,
    float* __restrict__ wt)
{
  int g = blockIdx.x * 256 + threadIdx.x;   // 0..98303  (= 6*16384)
  int mat = g >> 14;
  int r = g & 16383;
  int o = r >> 7;
  int i = r & 127;
  const float* s = w0;
  if (mat == 1) s = w1; else if (mat == 2) s = w2; else if (mat == 3) s = w3;
  else if (mat == 4) s = w4; else if (mat == 5) s = w5;
  float v = s[r];                       // W[o*128+i], coalesced read
  wt[mat * 16384 + i * 128 + o] = v;    // strided write, tiny one-time cost
}

// ------------------------------------------------------------- CSR build
// Harness uploads integer inputs as int32 — edge_index is const int*.
__global__ __launch_bounds__(256) void hist_kernel(
    const int* __restrict__ ei, int* __restrict__ counts)
{
  int e = blockIdx.x * 256 + threadIdx.x;
  if (e < NEDGES) {
    int d = ei[NEDGES + e];             // dst row of edge_index
    atomicAdd(&counts[d], 1);
  }
}

// Hierarchical scan of (counts[i]+1), 50000 elems, exclusive.
__global__ __launch_bounds__(256) void scan_part(
    const int* __restrict__ counts, int* __restrict__ part,
    int* __restrict__ bsum)
{
  __shared__ int sh[256];
  int t = threadIdx.x;
  int i = blockIdx.x * 256 + t;
  int v = (i < NNODES) ? counts[i] + 1 : 0;   // +1 = self loop slot
  sh[t] = v;
  __syncthreads();
  for (int off = 1; off < 256; off <<= 1) {
    int u = (t >= off) ? sh[t - off] : 0;
    __syncthreads();
    sh[t] += u;
    __syncthreads();
  }
  if (i < NNODES) part[i] = sh[t] - v;        // exclusive
  if (t == 255) bsum[blockIdx.x] = sh[255];
}

__global__ __launch_bounds__(256) void scan_bsums(int* __restrict__ bsum)
{
  __shared__ int sh[256];
  int t = threadIdx.x;
  int v = (t < NBLK) ? bsum[t] : 0;
  sh[t] = v;
  __syncthreads();
  for (int off = 1; off < 256; off <<= 1) {
    int u = (t >= off) ? sh[t - off] : 0;
    __syncthreads();
    sh[t] += u;
    __syncthreads();
  }
  if (t < NBLK) bsum[t] = sh[t] - v;          // exclusive
}

__global__ __launch_bounds__(256) void scan_final(
    const int* __restrict__ part, const int* __restrict__ bsum,
    int* __restrict__ rowptr, int* __restrict__ cursor)
{
  int i = blockIdx.x * 256 + threadIdx.x;
  if (i < NNODES) {
    int r = part[i] + bsum[blockIdx.x];
    rowptr[i] = r;
    cursor[i] = r;
  }
  if (i == 0) rowptr[NNODES] = NEDGES + NNODES;
}

__global__ __launch_bounds__(256) void scatter_kernel(
    const int* __restrict__ ei, int* __restrict__ cursor,
    int* __restrict__ col)
{
  int e = blockIdx.x * 256 + threadIdx.x;
  if (e < NEDGES + NNODES) {
    int s, d;
    if (e < NEDGES) { s = ei[e]; d = ei[NEDGES + e]; }
    else           { s = e - NEDGES; d = s; }   // self loop
    int slot = atomicAdd(&cursor[d], 1);
    col[slot] = s;
  }
}

// ------------------------------------------------------- fused dual GEMM
// xl[n][o] = sum_i h[n][i]*Wl[o][i];  xr likewise. wlT/wrT are [i][o].
// h tile stored TRANSPOSED in LDS: hst[i][n] (pad 68 -> 16B-aligned rows,
// row stride 68 words == 16 mod 32 banks: staging writes are 2-way = free).
// Main loop: 2x ds_read_b128 per i instead of 8x ds_read_b32.
__global__ __launch_bounds__(256, 4) void gemm_xlxr(
    const float* __restrict__ h, const float* __restrict__ wlT,
    const float* __restrict__ wrT, float* __restrict__ xl,
    float* __restrict__ xr)
{
  __shared__ float hst[128][68];         // 34.8 KB; 4 blocks/CU = 139 KB
  const int tid = threadIdx.x;
  const int n0 = blockIdx.x * 64;
  const float4* h4 = (const float4*)h;
#pragma unroll
  for (int it = 0; it < 8; ++it) {
    int f = it * 256 + tid;              // 0..2047
    int n = f >> 5;                      // 0..63
    int c = f & 31;                      // float4 column (i = 4c..4c+3)
    float4 v = make_float4(0.f, 0.f, 0.f, 0.f);
    if (n0 + n < NNODES) v = h4[(n0 + n) * 32 + c];
    hst[4 * c + 0][n] = v.x;
    hst[4 * c + 1][n] = v.y;
    hst[4 * c + 2][n] = v.z;
    hst[4 * c + 3][n] = v.w;
  }
  __syncthreads();

  const int to = tid & 31;               // o = to*4 .. to*4+3
  const int tg = tid >> 5;               // node group: n = tg*8 + j
  float4 accl[8], accr[8];
#pragma unroll
  for (int j = 0; j < 8; ++j) {
    accl[j] = make_float4(0.f, 0.f, 0.f, 0.f);
    accr[j] = make_float4(0.f, 0.f, 0.f, 0.f);
  }
  const float4* wl4 = (const float4*)wlT;
  const float4* wr4 = (const float4*)wrT;
#pragma unroll 2
  for (int i = 0; i < 128; ++i) {
    float4 wl = wl4[i * 32 + to];        // L2 resident (128 KB total)
    float4 wr = wr4[i * 32 + to];
    float4 h0 = *(const float4*)&hst[i][tg * 8];      // rows tg*8..+3
    float4 h1 = *(const float4*)&hst[i][tg * 8 + 4];  // rows tg*8+4..+7
    const float hv[8] = {h0.x, h0.y, h0.z, h0.w, h1.x, h1.y, h1.z, h1.w};
#pragma unroll
    for (int j = 0; j < 8; ++j) {
      accl[j].x = fmaf(hv[j], wl.x, accl[j].x);
      accl[j].y = fmaf(hv[j], wl.y, accl[j].y);
      accl[j].z = fmaf(hv[j], wl.z, accl[j].z);
      accl[j].w = fmaf(hv[j], wl.w, accl[j].w);
      accr[j].x = fmaf(hv[j], wr.x, accr[j].x);
      accr[j].y = fmaf(hv[j], wr.y, accr[j].y);
      accr[j].z = fmaf(hv[j], wr.z, accr[j].z);
      accr[j].w = fmaf(hv[j], wr.w, accr[j].w);
    }
  }
#pragma unroll
  for (int j = 0; j < 8; ++j) {
    int n = n0 + tg * 8 + j;
    if (n < NNODES) {
      ((float4*)xl)[n * 32 + to] = accl[j];
      ((float4*)xr)[n * 32 + to] = accr[j];
    }
  }
}

// ---------------------------------------- fused attention + aggregate + GELU
// One wave per dst node, split into two 32-lane halves; each half processes
// its own edge stream (4 feats/lane, float4 gathers, 5-step reduce).
// 2 independent online-softmax states per half; merged at the end.
// Sentinels are -FLT_MAX (NOT -inf) and masked edges use w=0 so no
// exp(-inf - -inf) NaN can occur.
struct OState4 { float mx, dn; float4 a; };

static __device__ __forceinline__ void upd4(
    OState4& st, float q, bool valid, const float4& v)
{
  float nm = fmaxf(st.mx, q);           // q finite (masked lanes pass -FLT_MAX)
  float sc = __expf(st.mx - nm);        // fresh state: exp(-huge)=0
  float w  = valid ? __expf(q - nm) : 0.f;
  st.dn = fmaf(st.dn, sc, w);
  st.a.x = fmaf(st.a.x, sc, w * v.x);
  st.a.y = fmaf(st.a.y, sc, w * v.y);
  st.a.z = fmaf(st.a.z, sc, w * v.z);
  st.a.w = fmaf(st.a.w, sc, w * v.w);
  st.mx = nm;
}

__global__ __launch_bounds__(256) void agg_kernel(
    const int* __restrict__ rowptr, const int* __restrict__ col,
    const float* __restrict__ xl, const float* __restrict__ xr,
    const float* __restrict__ att, const float* __restrict__ bias,
    float* __restrict__ hout)
{
  const int tid  = threadIdx.x;
  const int lane = tid & 63;
  const int half = lane >> 5;            // 0 or 1
  const int l32  = lane & 31;            // lane within half
  const int d    = blockIdx.x * 4 + (tid >> 6);

  const float4* xl4 = (const float4*)xl;
  float4 xrv = ((const float4*)xr)[d * 32 + l32];
  float4 av  = ((const float4*)att)[l32];
  int beg = rowptr[d], end = rowptr[d + 1];

  OState4 s0 = {-FLT_MAX, 0.f, {0.f, 0.f, 0.f, 0.f}};
  OState4 s1 = {-FLT_MAX, 0.f, {0.f, 0.f, 0.f, 0.f}};

  // half h takes edges beg+4t+2h+{0,1}
  for (int k0 = beg + 2 * half; k0 < end; k0 += 4) {
    int ka = k0, kb = k0 + 1;
    bool va = ka < end, vb = kb < end;
    int ca = col[va ? ka : beg];
    int cb = col[vb ? kb : beg];
    float4 a = xl4[ca * 32 + l32];       // 16B/lane gather
    float4 b = xl4[cb * 32 + l32];

    float4 ma, mb;
    ma.x = a.x + xrv.x; ma.y = a.y + xrv.y; ma.z = a.z + xrv.z; ma.w = a.w + xrv.w;
    mb.x = b.x + xrv.x; mb.y = b.y + xrv.y; mb.z = b.z + xrv.z; mb.w = b.w + xrv.w;
    ma.x = fmaxf(ma.x, 0.2f * ma.x); ma.y = fmaxf(ma.y, 0.2f * ma.y);
    ma.z = fmaxf(ma.z, 0.2f * ma.z); ma.w = fmaxf(ma.w, 0.2f * ma.w);
    mb.x = fmaxf(mb.x, 0.2f * mb.x); mb.y = fmaxf(mb.y, 0.2f * mb.y);
    mb.z = fmaxf(mb.z, 0.2f * mb.z); mb.w = fmaxf(mb.w, 0.2f * mb.w);
    float qa = fmaf(ma.x, av.x, fmaf(ma.y, av.y, fmaf(ma.z, av.z, ma.w * av.w)));
    float qb = fmaf(mb.x, av.x, fmaf(mb.y, av.y, fmaf(mb.z, av.z, mb.w * av.w)));
#pragma unroll
    for (int off = 16; off > 0; off >>= 1) {  // within-half reduce, 2 chains
      qa += __shfl_xor(qa, off, 64);
      qb += __shfl_xor(qb, off, 64);
    }
    if (!va) qa = -FLT_MAX;
    if (!vb) qb = -FLT_MAX;
    upd4(s0, qa, va, a);
    upd4(s1, qb, vb, b);
  }

  // merge s0,s1 within the half
  float M01 = fmaxf(s0.mx, s1.mx);              // >= -FLT_MAX, never NaN
  float e0 = __expf(s0.mx - M01), e1 = __expf(s1.mx - M01);
  float dn = s0.dn * e0 + s1.dn * e1;
  float4 ac;
  ac.x = s0.a.x * e0 + s1.a.x * e1;
  ac.y = s0.a.y * e0 + s1.a.y * e1;
  ac.z = s0.a.z * e0 + s1.a.z * e1;
  ac.w = s0.a.w * e0 + s1.a.w * e1;

  // merge across halves (xor 32)
  float Mo  = __shfl_xor(M01, 32, 64);
  float dno = __shfl_xor(dn, 32, 64);
  float aox = __shfl_xor(ac.x, 32, 64);
  float aoy = __shfl_xor(ac.y, 32, 64);
  float aoz = __shfl_xor(ac.z, 32, 64);
  float aow = __shfl_xor(ac.w, 32, 64);
  float M  = fmaxf(M01, Mo);
  float eA = __expf(M01 - M), eB = __expf(Mo - M);
  float den = dn * eA + dno * eB;
  float inv = 1.f / den;
  float4 bi = ((const float4*)bias)[l32];
  float o0 = fmaf((ac.x * eA + aox * eB), inv, bi.x);
  float o1 = fmaf((ac.y * eA + aoy * eB), inv, bi.y);
  float o2 = fmaf((ac.z * eA + aoz * eB), inv, bi.z);
  float o3 = fmaf((ac.w * eA + aow * eB), inv, bi.w);
  o0 = 0.5f * o0 * (1.f + erff(o0 * 0.70710678118654752f));
  o1 = 0.5f * o1 * (1.f + erff(o1 * 0.70710678118654752f));
  o2 = 0.5f * o2 * (1.f + erff(o2 * 0.70710678118654752f));
  o3 = 0.5f * o3 * (1.f + erff(o3 * 0.70710678118654752f));
  if (half == 0)
    ((float4*)hout)[d * 32 + l32] = make_float4(o0, o1, o2, o3);
}

// ------------------------------------------------------------------ launch
extern "C" void kernel_launch(void* const* d_in, const int* in_sizes, int n_in,
                              void* d_out, int out_size, void* d_ws, size_t ws_size,
                              hipStream_t stream)
{
  const float* x = (const float*)d_in[0];
  const int* ei = (const int*)d_in[1];     // int inputs arrive as int32
  const float *Wl[3], *Wr[3], *attv[3], *bv[3];
  for (int l = 0; l < 3; ++l) {
    Wl[l]   = (const float*)d_in[2 + 4 * l];
    Wr[l]   = (const float*)d_in[3 + 4 * l];
    attv[l] = (const float*)d_in[4 + 4 * l];
    bv[l]   = (const float*)d_in[5 + 4 * l];
  }

  char* base = (char*)d_ws;
  size_t off = 0;
  auto alloc = [&](size_t bytes) -> char* {
    char* p = base + off;
    off += (bytes + 255) & ~(size_t)255;
    return p;
  };
  float* wt     = (float*)alloc((size_t)6 * 16384 * 4);
  float* xl     = (float*)alloc((size_t)NNODES * 128 * 4);
  float* xr     = (float*)alloc((size_t)NNODES * 128 * 4);
  int* rowptr   = (int*)alloc((size_t)(NNODES + 1) * 4);
  int* cursor   = (int*)alloc((size_t)NNODES * 4);
  int* counts   = (int*)alloc((size_t)NNODES * 4);
  int* part     = (int*)alloc((size_t)(NBLK * 256) * 4);
  int* bsum     = (int*)alloc((size_t)256 * 4);
  int* col      = (int*)alloc((size_t)(NEDGES + NNODES) * 4);
  (void)ws_size; (void)in_sizes; (void)n_in; (void)out_size;

  hipMemsetAsync(counts, 0, (size_t)NNODES * 4, stream);
  transpose_w<<<384, 256, 0, stream>>>(Wl[0], Wr[0], Wl[1], Wr[1], Wl[2], Wr[2], wt);
  hist_kernel<<<(NEDGES + 255) / 256, 256, 0, stream>>>(ei, counts);
  scan_part<<<NBLK, 256, 0, stream>>>(counts, part, bsum);
  scan_bsums<<<1, 256, 0, stream>>>(bsum);
  scan_final<<<NBLK, 256, 0, stream>>>(part, bsum, rowptr, cursor);
  scatter_kernel<<<(NEDGES + NNODES + 255) / 256, 256, 0, stream>>>(ei, cursor, col);

  // h ping-pongs through d_out: each layer's GEMM consumes h before agg
  // overwrites it, and agg never reads its own output buffer.
  float* dout = (float*)d_out;
  const float* hin = x;
  for (int l = 0; l < 3; ++l) {
    gemm_xlxr<<<(NNODES + 63) / 64, 256, 0, stream>>>(
        hin, wt + (size_t)(2 * l) * 16384, wt + (size_t)(2 * l + 1) * 16384, xl, xr);
    agg_kernel<<<NNODES / 4, 256, 0, stream>>>(
        rowptr, col, xl, xr, attv[l], bv[l], dout);
    hin = dout;
  }
}

// Round 5
// 507.746 us; speedup vs baseline: 1.6119x; 1.0716x over previous
//
#include <hip/hip_runtime.h>
#include <math.h>
#include <float.h>

#define NNODES 50000
#define NPAD   50048   // 782*64, rows the MFMA gemm may touch
#define NEDGES 800000
#define NBLK 196       // ceil(50000/256)
// D = 128 fixed

typedef __attribute__((ext_vector_type(8))) short bfrag;   // 8 bf16 (4 VGPR)
typedef __attribute__((ext_vector_type(4))) float ffrag;   // 4 fp32 acc

// ---------------------------------------------------------------- bf16 split
// v ~= hi + lo, both RN-bf16. |v - hi - lo| <~ 2^-17 |v|.
static __device__ __forceinline__ void bsplit(float f, ushort& h, ushort& l) {
  unsigned u = __float_as_uint(f);
  unsigned hb = (u + 0x7FFFu + ((u >> 16) & 1u)) >> 16;
  h = (ushort)hb;
  float r = f - __uint_as_float(hb << 16);
  unsigned v = __float_as_uint(r);
  l = (ushort)((v + 0x7FFFu + ((v >> 16) & 1u)) >> 16);
}

// --------------------------------------------- W -> bf16 planes (row-major)
// B layout per layer: rows 0..127 = Wl[n][k], rows 128..255 = Wr[n][k].
// out idx = layer*32768 + half*16384 + r  (r = n_local*128 + k)
__global__ __launch_bounds__(256) void convert_w(
    const float* __restrict__ w0, const float* __restrict__ w1,
    const float* __restrict__ w2, const float* __restrict__ w3,
    const float* __restrict__ w4, const float* __restrict__ w5,
    ushort* __restrict__ bhi, ushort* __restrict__ blo)
{
  int g = blockIdx.x * 256 + threadIdx.x;   // 0..98303
  int mat = g >> 14;                        // 0..5 : Wl0,Wr0,Wl1,Wr1,Wl2,Wr2
  int r = g & 16383;
  const float* s = w0;
  if (mat == 1) s = w1; else if (mat == 2) s = w2; else if (mat == 3) s = w3;
  else if (mat == 4) s = w4; else if (mat == 5) s = w5;
  ushort h, l;
  bsplit(s[r], h, l);
  int o = (mat >> 1) * 32768 + (mat & 1) * 16384 + r;
  bhi[o] = h;
  blo[o] = l;
}

// --------------------------------------------- x -> bf16 planes (row-major)
__global__ __launch_bounds__(256) void convert_x(
    const float* __restrict__ x, ushort* __restrict__ ahi,
    ushort* __restrict__ alo)
{
  int idx = blockIdx.x * 256 + threadIdx.x;      // over 50000*32 float4s
  if (idx >= NNODES * 32) return;
  float4 v = ((const float4*)x)[idx];
  ushort h0,l0,h1,l1,h2,l2,h3,l3;
  bsplit(v.x, h0, l0); bsplit(v.y, h1, l1);
  bsplit(v.z, h2, l2); bsplit(v.w, h3, l3);
  ushort4 hv = {h0, h1, h2, h3};
  ushort4 lv = {l0, l1, l2, l3};
  ((ushort4*)ahi)[idx] = hv;
  ((ushort4*)alo)[idx] = lv;
}

// ------------------------------------------------------------- CSR build
// Harness uploads integer inputs as int32 — edge_index is const int*.
__global__ __launch_bounds__(256) void hist_kernel(
    const int* __restrict__ ei, int* __restrict__ counts)
{
  int e = blockIdx.x * 256 + threadIdx.x;
  if (e < NEDGES) {
    int d = ei[NEDGES + e];
    atomicAdd(&counts[d], 1);
  }
}

__global__ __launch_bounds__(256) void scan_part(
    const int* __restrict__ counts, int* __restrict__ part,
    int* __restrict__ bsum)
{
  __shared__ int sh[256];
  int t = threadIdx.x;
  int i = blockIdx.x * 256 + t;
  int v = (i < NNODES) ? counts[i] + 1 : 0;   // +1 = self loop slot
  sh[t] = v;
  __syncthreads();
  for (int off = 1; off < 256; off <<= 1) {
    int u = (t >= off) ? sh[t - off] : 0;
    __syncthreads();
    sh[t] += u;
    __syncthreads();
  }
  if (i < NNODES) part[i] = sh[t] - v;
  if (t == 255) bsum[blockIdx.x] = sh[255];
}

__global__ __launch_bounds__(256) void scan_bsums(int* __restrict__ bsum)
{
  __shared__ int sh[256];
  int t = threadIdx.x;
  int v = (t < NBLK) ? bsum[t] : 0;
  sh[t] = v;
  __syncthreads();
  for (int off = 1; off < 256; off <<= 1) {
    int u = (t >= off) ? sh[t - off] : 0;
    __syncthreads();
    sh[t] += u;
    __syncthreads();
  }
  if (t < NBLK) bsum[t] = sh[t] - v;
}

__global__ __launch_bounds__(256) void scan_final(
    const int* __restrict__ part, const int* __restrict__ bsum,
    int* __restrict__ rowptr, int* __restrict__ cursor)
{
  int i = blockIdx.x * 256 + threadIdx.x;
  if (i < NNODES) {
    int r = part[i] + bsum[blockIdx.x];
    rowptr[i] = r;
    cursor[i] = r;
  }
  if (i == 0) rowptr[NNODES] = NEDGES + NNODES;
}

__global__ __launch_bounds__(256) void scatter_kernel(
    const int* __restrict__ ei, int* __restrict__ cursor,
    int* __restrict__ col)
{
  int e = blockIdx.x * 256 + threadIdx.x;
  if (e < NEDGES + NNODES) {
    int s, d;
    if (e < NEDGES) { s = ei[e]; d = ei[NEDGES + e]; }
    else           { s = e - NEDGES; d = s; }   // self loop
    int slot = atomicAdd(&cursor[d], 1);
    col[slot] = s;
  }
}

// ------------------------------------------------- MFMA split-bf16 dual GEMM
// xl[m][n] = sum_k h[m][k] Wl[n][k]; xr likewise; computed as one M x 256 GEMM
// with B = [Wl ; Wr], C = Ah.Bh + Ah.Bl + Al.Bh (fp32 acc, Al.Bl dropped).
// A-frag: A[m = lane&15][k = (lane>>4)*8 + j]  -> 16B contiguous from plane.
// B-frag mirrors with n = lane&15. D: col(n)=lane&15, row(m)=(lane>>4)*4+reg.
// Block = 4 waves; wave w covers n in [64w, 64w+64); M-tile 64 rows.
__global__ __launch_bounds__(256) void gemm_mfma(
    const ushort* __restrict__ ahi, const ushort* __restrict__ alo,
    const ushort* __restrict__ bhi, const ushort* __restrict__ blo,
    float* __restrict__ xl, float* __restrict__ xr)
{
  const int wave = threadIdx.x >> 6;
  const int lane = threadIdx.x & 63;
  const int l16  = lane & 15;
  const int kq   = lane >> 4;              // 0..3
  const int m0   = blockIdx.x * 64;

  ffrag acc[4][4];
#pragma unroll
  for (int mt = 0; mt < 4; ++mt)
#pragma unroll
    for (int nt = 0; nt < 4; ++nt)
      acc[mt][nt] = (ffrag){0.f, 0.f, 0.f, 0.f};

#pragma unroll
  for (int kb = 0; kb < 4; ++kb) {
    const int k0 = kb * 32 + kq * 8;
    bfrag ah[4], al[4], bh[4], bl[4];
#pragma unroll
    for (int mt = 0; mt < 4; ++mt) {
      int m = m0 + mt * 16 + l16;          // < NPAD (planes padded)
      ah[mt] = *(const bfrag*)&ahi[m * 128 + k0];
      al[mt] = *(const bfrag*)&alo[m * 128 + k0];
    }
#pragma unroll
    for (int nt = 0; nt < 4; ++nt) {
      int n = wave * 64 + nt * 16 + l16;   // 0..255
      bh[nt] = *(const bfrag*)&bhi[n * 128 + k0];
      bl[nt] = *(const bfrag*)&blo[n * 128 + k0];
    }
#pragma unroll
    for (int mt = 0; mt < 4; ++mt)
#pragma unroll
      for (int nt = 0; nt < 4; ++nt) {
        acc[mt][nt] = __builtin_amdgcn_mfma_f32_16x16x32_bf16(
            ah[mt], bh[nt], acc[mt][nt], 0, 0, 0);
        acc[mt][nt] = __builtin_amdgcn_mfma_f32_16x16x32_bf16(
            ah[mt], bl[nt], acc[mt][nt], 0, 0, 0);
        acc[mt][nt] = __builtin_amdgcn_mfma_f32_16x16x32_bf16(
            al[mt], bh[nt], acc[mt][nt], 0, 0, 0);
      }
  }

#pragma unroll
  for (int mt = 0; mt < 4; ++mt) {
    int mb = m0 + mt * 16 + kq * 4;
#pragma unroll
    for (int nt = 0; nt < 4; ++nt) {
      int ng = wave * 64 + nt * 16 + l16;
      float* dst = (ng < 128) ? xl : xr;
      int n = ng & 127;
#pragma unroll
      for (int r = 0; r < 4; ++r) {
        int m = mb + r;
        if (m < NNODES) dst[m * 128 + n] = acc[mt][nt][r];
      }
    }
  }
}

// ---------------------------------------- fused attention + aggregate + GELU
// One wave per dst node, two 32-lane halves, each with its own edge stream
// (4 feats/lane float4 gathers, 5-step reduce, 2 online-softmax states).
// Epilogue: bias + exact GELU; writes bf16 hi/lo planes (layers 0,1) or
// fp32 output (last layer).
struct OState4 { float mx, dn; float4 a; };

static __device__ __forceinline__ void upd4(
    OState4& st, float q, bool valid, const float4& v)
{
  float nm = fmaxf(st.mx, q);
  float sc = __expf(st.mx - nm);
  float w  = valid ? __expf(q - nm) : 0.f;
  st.dn = fmaf(st.dn, sc, w);
  st.a.x = fmaf(st.a.x, sc, w * v.x);
  st.a.y = fmaf(st.a.y, sc, w * v.y);
  st.a.z = fmaf(st.a.z, sc, w * v.z);
  st.a.w = fmaf(st.a.w, sc, w * v.w);
  st.mx = nm;
}

__global__ __launch_bounds__(256) void agg_kernel(
    const int* __restrict__ rowptr, const int* __restrict__ col,
    const float* __restrict__ xl, const float* __restrict__ xr,
    const float* __restrict__ att, const float* __restrict__ bias,
    float* __restrict__ hout, ushort* __restrict__ ahi,
    ushort* __restrict__ alo, int last)
{
  const int tid  = threadIdx.x;
  const int lane = tid & 63;
  const int half = lane >> 5;
  const int l32  = lane & 31;
  const int d    = blockIdx.x * 4 + (tid >> 6);

  const float4* xl4 = (const float4*)xl;
  float4 xrv = ((const float4*)xr)[d * 32 + l32];
  float4 av  = ((const float4*)att)[l32];
  int beg = rowptr[d], end = rowptr[d + 1];

  OState4 s0 = {-FLT_MAX, 0.f, {0.f, 0.f, 0.f, 0.f}};
  OState4 s1 = {-FLT_MAX, 0.f, {0.f, 0.f, 0.f, 0.f}};

  for (int k0 = beg + 2 * half; k0 < end; k0 += 4) {
    int ka = k0, kb = k0 + 1;
    bool va = ka < end, vb = kb < end;
    int ca = col[va ? ka : beg];
    int cb = col[vb ? kb : beg];
    float4 a = xl4[ca * 32 + l32];
    float4 b = xl4[cb * 32 + l32];

    float4 ma, mb;
    ma.x = a.x + xrv.x; ma.y = a.y + xrv.y; ma.z = a.z + xrv.z; ma.w = a.w + xrv.w;
    mb.x = b.x + xrv.x; mb.y = b.y + xrv.y; mb.z = b.z + xrv.z; mb.w = b.w + xrv.w;
    ma.x = fmaxf(ma.x, 0.2f * ma.x); ma.y = fmaxf(ma.y, 0.2f * ma.y);
    ma.z = fmaxf(ma.z, 0.2f * ma.z); ma.w = fmaxf(ma.w, 0.2f * ma.w);
    mb.x = fmaxf(mb.x, 0.2f * mb.x); mb.y = fmaxf(mb.y, 0.2f * mb.y);
    mb.z = fmaxf(mb.z, 0.2f * mb.z); mb.w = fmaxf(mb.w, 0.2f * mb.w);
    float qa = fmaf(ma.x, av.x, fmaf(ma.y, av.y, fmaf(ma.z, av.z, ma.w * av.w)));
    float qb = fmaf(mb.x, av.x, fmaf(mb.y, av.y, fmaf(mb.z, av.z, mb.w * av.w)));
#pragma unroll
    for (int off = 16; off > 0; off >>= 1) {
      qa += __shfl_xor(qa, off, 64);
      qb += __shfl_xor(qb, off, 64);
    }
    if (!va) qa = -FLT_MAX;
    if (!vb) qb = -FLT_MAX;
    upd4(s0, qa, va, a);
    upd4(s1, qb, vb, b);
  }

  float M01 = fmaxf(s0.mx, s1.mx);
  float e0 = __expf(s0.mx - M01), e1 = __expf(s1.mx - M01);
  float dn = s0.dn * e0 + s1.dn * e1;
  float4 ac;
  ac.x = s0.a.x * e0 + s1.a.x * e1;
  ac.y = s0.a.y * e0 + s1.a.y * e1;
  ac.z = s0.a.z * e0 + s1.a.z * e1;
  ac.w = s0.a.w * e0 + s1.a.w * e1;

  float Mo  = __shfl_xor(M01, 32, 64);
  float dno = __shfl_xor(dn, 32, 64);
  float aox = __shfl_xor(ac.x, 32, 64);
  float aoy = __shfl_xor(ac.y, 32, 64);
  float aoz = __shfl_xor(ac.z, 32, 64);
  float aow = __shfl_xor(ac.w, 32, 64);
  float M  = fmaxf(M01, Mo);
  float eA = __expf(M01 - M), eB = __expf(Mo - M);
  float den = dn * eA + dno * eB;
  float inv = 1.f / den;
  float4 bi = ((const float4*)bias)[l32];
  float o0 = fmaf((ac.x * eA + aox * eB), inv, bi.x);
  float o1 = fmaf((ac.y * eA + aoy * eB), inv, bi.y);
  float o2 = fmaf((ac.z * eA + aoz * eB), inv, bi.z);
  float o3 = fmaf((ac.w * eA + aow * eB), inv, bi.w);
  o0 = 0.5f * o0 * (1.f + erff(o0 * 0.70710678118654752f));
  o1 = 0.5f * o1 * (1.f + erff(o1 * 0.70710678118654752f));
  o2 = 0.5f * o2 * (1.f + erff(o2 * 0.70710678118654752f));
  o3 = 0.5f * o3 * (1.f + erff(o3 * 0.70710678118654752f));
  if (half == 0) {
    if (last) {
      ((float4*)hout)[d * 32 + l32] = make_float4(o0, o1, o2, o3);
    } else {
      ushort h0,l0,h1,l1,h2,l2,h3,l3;
      bsplit(o0, h0, l0); bsplit(o1, h1, l1);
      bsplit(o2, h2, l2); bsplit(o3, h3, l3);
      ushort4 hv = {h0, h1, h2, h3};
      ushort4 lv = {l0, l1, l2, l3};
      ((ushort4*)ahi)[d * 32 + l32] = hv;
      ((ushort4*)alo)[d * 32 + l32] = lv;
    }
  }
}

// ------------------------------------------------------------------ launch
extern "C" void kernel_launch(void* const* d_in, const int* in_sizes, int n_in,
                              void* d_out, int out_size, void* d_ws, size_t ws_size,
                              hipStream_t stream)
{
  const float* x = (const float*)d_in[0];
  const int* ei = (const int*)d_in[1];     // int inputs arrive as int32
  const float *Wl[3], *Wr[3], *attv[3], *bv[3];
  for (int l = 0; l < 3; ++l) {
    Wl[l]   = (const float*)d_in[2 + 4 * l];
    Wr[l]   = (const float*)d_in[3 + 4 * l];
    attv[l] = (const float*)d_in[4 + 4 * l];
    bv[l]   = (const float*)d_in[5 + 4 * l];
  }

  char* base = (char*)d_ws;
  size_t off = 0;
  auto alloc = [&](size_t bytes) -> char* {
    char* p = base + off;
    off += (bytes + 255) & ~(size_t)255;
    return p;
  };
  ushort* ahi  = (ushort*)alloc((size_t)NPAD * 128 * 2);   // 12.8 MB
  ushort* alo  = (ushort*)alloc((size_t)NPAD * 128 * 2);
  ushort* bhi  = (ushort*)alloc((size_t)3 * 256 * 128 * 2); // 196 KB
  ushort* blo  = (ushort*)alloc((size_t)3 * 256 * 128 * 2);
  float* xl    = (float*)alloc((size_t)NNODES * 128 * 4);  // 25.6 MB
  int* rowptr  = (int*)alloc((size_t)(NNODES + 1) * 4);
  int* cursor  = (int*)alloc((size_t)NNODES * 4);
  int* counts  = (int*)alloc((size_t)NNODES * 4);
  int* part    = (int*)alloc((size_t)(NBLK * 256) * 4);
  int* bsum    = (int*)alloc((size_t)256 * 4);
  int* col     = (int*)alloc((size_t)(NEDGES + NNODES) * 4);
  float* xr    = (float*)d_out;   // aliased: agg wave reads its xr row before
                                  // writing the same row; no cross-row hazard.
  (void)ws_size; (void)in_sizes; (void)n_in; (void)out_size;

  hipMemsetAsync(counts, 0, (size_t)NNODES * 4, stream);
  convert_w<<<384, 256, 0, stream>>>(Wl[0], Wr[0], Wl[1], Wr[1], Wl[2], Wr[2],
                                     bhi, blo);
  convert_x<<<(NNODES * 32 + 255) / 256, 256, 0, stream>>>(x, ahi, alo);
  hist_kernel<<<(NEDGES + 255) / 256, 256, 0, stream>>>(ei, counts);
  scan_part<<<NBLK, 256, 0, stream>>>(counts, part, bsum);
  scan_bsums<<<1, 256, 0, stream>>>(bsum);
  scan_final<<<NBLK, 256, 0, stream>>>(part, bsum, rowptr, cursor);
  scatter_kernel<<<(NEDGES + NNODES + 255) / 256, 256, 0, stream>>>(ei, cursor, col);

  for (int l = 0; l < 3; ++l) {
    gemm_mfma<<<NPAD / 64, 256, 0, stream>>>(
        ahi, alo, bhi + (size_t)l * 32768, blo + (size_t)l * 32768, xl, xr);
    agg_kernel<<<NNODES / 4, 256, 0, stream>>>(
        rowptr, col, xl, xr, attv[l], bv[l], (float*)d_out, ahi, alo,
        (l == 2) ? 1 : 0);
  }
}